// Round 18
// baseline (84.730 us; speedup 1.0000x reference)
//
#include <hip/hip_runtime.h>
#include <stdint.h>

#define BB 4
#define CC 64
#define HH 192
#define WW 192
#define HWN (HH*WW)            // 36864
#define KH 4
#define KW 16
#define PW (WW/KW)             // 12
#define MP ((HH/KH)*(WW/KW))   // 576
#define MITER (MP/64)          // 9
#define NBTOT (HWN/32)         // 1152 32-row n-blocks per batch
#define NUNIT (HWN/64)         // 576 64-row units per batch (colsum)
#define NGRP 36                // reduce level-A groups (16 un each)
#define SCALE_W 65536.0f
#define INV_SCALE (1.0f/65536.0f)
#define LOG2E 1.44269504088896f

typedef _Float16 half8 __attribute__((ext_vector_type(8)));
typedef float floatx4 __attribute__((ext_vector_type(4)));

// async global->LDS, 16B per lane; LDS dest = uniform base + lane*16 (HW rule)
static __device__ __forceinline__ void gload16(const void* g, void* l) {
  __builtin_amdgcn_global_load_lds((const __attribute__((address_space(1))) void*)g,
                                   (__attribute__((address_space(3))) void*)l, 16, 0, 0);
}
#define WAITCNT_VM(N) asm volatile("s_waitcnt vmcnt(" #N ")" ::: "memory")

// fast 2^x: raw v_exp_f32 (libm exp2f costs ~15 VALU ops without fast-math)
static __device__ __forceinline__ float fexp2(float x) {
#if __has_builtin(__builtin_amdgcn_exp2f)
  return __builtin_amdgcn_exp2f(x);
#else
  return __expf(x * 0.6931471805599453f);
#endif
}

// Layouts (frag slot = chunk*512 + (lhi*16+l15)*8 + e, f16):
// kptF chunk=(mi*4+mf)*2+ks : Kp[b][m=mi*64+mf*16+l15][c=ks*32+lhi*8+e] * LOG2E
// qF   chunk=(b*NBTOT+nb)*4+ks*2+nf : Q[b][c=ks*32+lhi*8+e][n=nb*32+nf*16+l15]
// wqF  chunk=(mi*4+cf)*2+ks : W'[b][c=cf*16+l15][m=mi*64+ks*32+16*(e>>2)+lhi*4+(e&3)]
//   (sigma k-order: GEMM2's B-operand (E^T) is the IN-LANE repack of swapped-
//    GEMM1's accumulator -- slot e of window ks = exp2(sacc[2ks+(e>>2)][nf][e&3]))

// ---------------- pooling: kptF (f16 frag-order, xLOG2E) and Vp ------------
__global__ __launch_bounds__(256) void pool_kernel(
    const float* __restrict__ Kin, const float* __restrict__ Vin,
    _Float16* __restrict__ kptF, float* __restrict__ vp) {
  int t = blockIdx.x * 256 + threadIdx.x;
  const int total = BB * CC * MP;
  bool isV = t >= total;
  int idx = isV ? t - total : t;
  int m = idx % MP;
  int c = (idx / MP) % CC;
  int b = idx / (MP * CC);
  int mh = m / PW, mw = m % PW;
  const float* src = (isV ? Vin : Kin) + (((b * CC + c) * HH + mh * KH) * WW + mw * KW);
  float s = 0.f;
#pragma unroll
  for (int r = 0; r < KH; ++r) {
    const float4* row = (const float4*)(src + r * WW);
#pragma unroll
    for (int j = 0; j < KW / 4; ++j) {
      float4 v = row[j];
      s += v.x + v.y + v.z + v.w;
    }
  }
  s *= (1.0f / (KH * KW));
  if (isV) {
    vp[(b * CC + c) * MP + m] = s;
  } else {
    int mi = m >> 6, w = m & 63, mf = w >> 4, l15 = w & 15;
    int ks = c >> 5, lhi = (c >> 3) & 3, e = c & 7;
    int lane = lhi * 16 + l15;
    kptF[((((b * MITER + mi) * 4 + mf) * 2 + ks) * 64 + lane) * 8 + e] =
        (_Float16)(s * LOG2E);
  }
}

// ---------------- Q -> f16 fragment order (one-time streaming transform) ---
__global__ __launch_bounds__(256) void qprep_kernel(
    const float* __restrict__ Q, _Float16* __restrict__ qF) {
  int t = blockIdx.x * 256 + threadIdx.x;
  int chunk = t >> 6;            // wave-uniform
  int lane = t & 63;
  int nf = chunk & 1;
  int ks = (chunk >> 1) & 1;
  int idx = chunk >> 2;          // b*NBTOT + nb
  int nb = idx % NBTOT;
  int b = idx / NBTOT;
  int c0 = ks * 32 + (lane >> 4) * 8;
  int n = nb * 32 + nf * 16 + (lane & 15);
  const float* Qb = Q + (b * CC + c0) * HWN + n;
  half8 h;
#pragma unroll
  for (int e = 0; e < 8; ++e) h[e] = (_Float16)Qb[e * HWN];
  *(half8*)(qF + chunk * 512 + lane * 8) = h;
}

// ---------------- pass A1: partial colsum (qF once per wave) ---------------
__global__ __launch_bounds__(256) void colsum_qf2_kernel(
    const _Float16* __restrict__ qF, const _Float16* __restrict__ kptF,
    float* __restrict__ part) {
  int tid = threadIdx.x;
  int lane = tid & 63;
  int l15 = lane & 15;
  int u = blockIdx.x * 4 + (tid >> 6);   // 0..BB*NUNIT-1
  int b = u / NUNIT;
  int un = u % NUNIT;

  const _Float16* qc = qF + (size_t)((b * NBTOT + un * 2) * 4) * 512 + lane * 8;
  half8 af[2][2][2];  // [nb][nf][ks]
#pragma unroll
  for (int nb = 0; nb < 2; ++nb)
#pragma unroll
    for (int ks = 0; ks < 2; ++ks)
#pragma unroll
      for (int nf = 0; nf < 2; ++nf)
        af[nb][nf][ks] = *(const half8*)(qc + (nb * 4 + ks * 2 + nf) * 512);

  const _Float16* kb = kptF + b * MITER * 8 * 512;
  floatx4 zero = {0.f, 0.f, 0.f, 0.f};
  float* pout = part + (size_t)(b * NUNIT + un) * MP;

#pragma unroll
  for (int mi = 0; mi < MITER; ++mi) {
    half8 bfr[4][2];
#pragma unroll
    for (int mf = 0; mf < 4; ++mf)
#pragma unroll
      for (int ks = 0; ks < 2; ++ks)
        bfr[mf][ks] = *(const half8*)(kb + ((mi * 4 + mf) * 2 + ks) * 512 + lane * 8);

    float s0 = 0.f, s1 = 0.f, s2 = 0.f, s3 = 0.f;
#pragma unroll
    for (int nb = 0; nb < 2; ++nb) {
      floatx4 sacc[2][4];
#pragma unroll
      for (int nf = 0; nf < 2; ++nf)
#pragma unroll
        for (int mf = 0; mf < 4; ++mf) sacc[nf][mf] = zero;
      __builtin_amdgcn_s_setprio(1);
#pragma unroll
      for (int ks = 0; ks < 2; ++ks)
#pragma unroll
        for (int nf = 0; nf < 2; ++nf)
#pragma unroll
          for (int mf = 0; mf < 4; ++mf)
            sacc[nf][mf] = __builtin_amdgcn_mfma_f32_16x16x32_f16(
                af[nb][nf][ks], bfr[mf][ks], sacc[nf][mf], 0, 0, 0);
      __builtin_amdgcn_s_setprio(0);
#pragma unroll
      for (int nf = 0; nf < 2; ++nf)
#pragma unroll
        for (int r = 0; r < 4; ++r) {
          s0 += fexp2(sacc[nf][0][r]);
          s1 += fexp2(sacc[nf][1][r]);
          s2 += fexp2(sacc[nf][2][r]);
          s3 += fexp2(sacc[nf][3][r]);
        }
    }
    s0 += __shfl_xor(s0, 16); s0 += __shfl_xor(s0, 32);
    s1 += __shfl_xor(s1, 16); s1 += __shfl_xor(s1, 32);
    s2 += __shfl_xor(s2, 16); s2 += __shfl_xor(s2, 32);
    s3 += __shfl_xor(s3, 16); s3 += __shfl_xor(s3, 32);
    if (lane < 16) {
      float* p = pout + mi * 64;
      p[0 * 16 + l15] = s0;   // m = mi*64 + mf*16 + l15
      p[1 * 16 + l15] = s1;
      p[2 * 16 + l15] = s2;
      p[3 * 16 + l15] = s3;
    }
  }
}

// ---------------- pass A2a: level-A reduce (144 blocks, 16 un each) --------
__global__ __launch_bounds__(576) void colsum_reduceA_kernel(
    const float* __restrict__ part, float* __restrict__ part2) {
  int m = threadIdx.x;           // 0..575
  int g = blockIdx.x;            // 0..35
  int b = blockIdx.y;
  const float* p = part + (size_t)(b * NUNIT + g * 16) * MP + m;
  float a0 = 0.f, a1 = 0.f, a2 = 0.f, a3 = 0.f;
#pragma unroll
  for (int j = 0; j < 16; j += 4) {
    a0 += p[(size_t)(j + 0) * MP];
    a1 += p[(size_t)(j + 1) * MP];
    a2 += p[(size_t)(j + 2) * MP];
    a3 += p[(size_t)(j + 3) * MP];
  }
  part2[(size_t)(b * NGRP + g) * MP + m] = (a0 + a1) + (a2 + a3);
}

// ---------------- pass A2b: level-B reduce (36 summands) -------------------
__global__ __launch_bounds__(256) void colsum_reduceB_kernel(
    const float* __restrict__ part2, float* __restrict__ colsum) {
  int t = blockIdx.x * 256 + threadIdx.x;  // 0..2303
  int m = t % MP;
  int b = t / MP;
  const float* p = part2 + (size_t)b * NGRP * MP + m;
  float a0 = 0.f, a1 = 0.f, a2 = 0.f, a3 = 0.f;
#pragma unroll
  for (int g = 0; g < NGRP; g += 4) {
    a0 += p[(size_t)(g + 0) * MP];
    a1 += p[(size_t)(g + 1) * MP];
    a2 += p[(size_t)(g + 2) * MP];
    a3 += p[(size_t)(g + 3) * MP];
  }
  colsum[t] = (a0 + a1) + (a2 + a3);
}

// ---------------- W' = Vp/colsum * 2^16 (f16, sigma-permuted k-order) ------
__global__ __launch_bounds__(256) void wprep_kernel(
    const float* __restrict__ vp, const float* __restrict__ colsum,
    _Float16* __restrict__ wqF) {
  int t = blockIdx.x * 256 + threadIdx.x;
  int m = t % MP;
  int c = (t / MP) % CC;
  int b = t / (CC * MP);
  float w = vp[t] / colsum[b * MP + m] * SCALE_W;
  int cf = c >> 4, l15 = c & 15;
  int mi = m >> 6, wl = m & 63;
  int ks = wl >> 5, v = wl & 31;
  int lhi = (v & 15) >> 2;
  int e = (v >> 4) * 4 + (v & 3);
  int lane = lhi * 16 + l15;
  wqF[((((b * MITER + mi) * 4 + cf) * 2 + ks) * 64 + lane) * 8 + e] = (_Float16)w;
}

// ---------------- pass B: attn v4 — 64 n-rows per wave ---------------------
// Two independent {GEMM1 -> fexp2 -> GEMM2} chains (j=0,1) per staged tile:
// halves LDS-read traffic per MFMA (663->332MB) and barrier count per work,
// and gives the scheduler cross-chain ILP (j1's MFMA under j0's exp).
__global__ __launch_bounds__(256) void attn_v4_kernel(
    const _Float16* __restrict__ qF, const _Float16* __restrict__ kptF,
    const _Float16* __restrict__ wqF, float* __restrict__ out) {
  __shared__ char stg[2 * 16384];
  int b = blockIdx.y;
  int tid = threadIdx.x;
  int wv = tid >> 6;
  int lane = tid & 63;
  int l15 = lane & 15, lhi = lane >> 4;

  const _Float16* kb = kptF + b * MITER * 8 * 512;
  const _Float16* wb = wqF + b * MITER * 8 * 512;

#define STAGE_V4(tt, ss)                                                       \
  {                                                                            \
    int q0_ = wv * 4;                                                          \
    _Pragma("unroll") for (int j_ = 0; j_ < 4; ++j_) {                         \
      int q_ = q0_ + j_;                                                       \
      const _Float16* sp_ = (q_ < 8 ? kb + (tt) * 4096 + q_ * 512              \
                                    : wb + (tt) * 4096 + (q_ - 8) * 512) +     \
                            lane * 8;                                          \
      gload16(sp_, stg + (ss) * 16384 + q_ * 1024);                            \
    }                                                                          \
  }

  STAGE_V4(0, 0);

  int nb0 = blockIdx.x * 8 + wv * 2;   // wave owns n-blocks nb0, nb0+1
  const _Float16* qc = qF + (size_t)((b * NBTOT + nb0) * 4) * 512 + lane * 8;
  half8 afrag[2][2][2];  // [j][nf][ks]
#pragma unroll
  for (int j = 0; j < 2; ++j)
#pragma unroll
    for (int ks = 0; ks < 2; ++ks)
#pragma unroll
      for (int nf = 0; nf < 2; ++nf)
        afrag[j][nf][ks] = *(const half8*)(qc + (j * 4 + ks * 2 + nf) * 512);

  floatx4 zero = {0.f, 0.f, 0.f, 0.f};
  floatx4 oacc[2][4][2];  // [j][cf][nf]
#pragma unroll
  for (int j = 0; j < 2; ++j)
#pragma unroll
    for (int cf = 0; cf < 4; ++cf)
#pragma unroll
      for (int nf = 0; nf < 2; ++nf) oacc[j][cf][nf] = zero;

#pragma unroll
  for (int mi = 0; mi < MITER; ++mi) {
    const int sc = mi & 1;
    WAITCNT_VM(0);
    __builtin_amdgcn_sched_barrier(0);
    __builtin_amdgcn_s_barrier();
    if (mi + 1 < MITER) STAGE_V4(mi + 1, sc ^ 1);

    half8 bfr[4][2];  // kpt A-operand: rows m
#pragma unroll
    for (int mf = 0; mf < 4; ++mf)
#pragma unroll
      for (int ks = 0; ks < 2; ++ks)
        bfr[mf][ks] = *(const half8*)(stg + sc * 16384 + (mf * 2 + ks) * 1024 + lane * 16);
    half8 wfr[4][2];  // W' A-operand (sigma k-order)
#pragma unroll
    for (int cf = 0; cf < 4; ++cf)
#pragma unroll
      for (int ks = 0; ks < 2; ++ks)
        wfr[cf][ks] = *(const half8*)(stg + sc * 16384 + 8192 + (cf * 2 + ks) * 1024 + lane * 16);

#pragma unroll
    for (int j = 0; j < 2; ++j) {
      // GEMM1 (swapped): sacc[mf][nf] = S^T tile for n-block nb0+j
      floatx4 sacc[4][2];
#pragma unroll
      for (int mf = 0; mf < 4; ++mf)
#pragma unroll
        for (int nf = 0; nf < 2; ++nf) sacc[mf][nf] = zero;
      __builtin_amdgcn_s_setprio(1);
#pragma unroll
      for (int ks = 0; ks < 2; ++ks)
#pragma unroll
        for (int mf = 0; mf < 4; ++mf)
#pragma unroll
          for (int nf = 0; nf < 2; ++nf)
            sacc[mf][nf] = __builtin_amdgcn_mfma_f32_16x16x32_f16(
                bfr[mf][ks], afrag[j][nf][ks], sacc[mf][nf], 0, 0, 0);
      __builtin_amdgcn_s_setprio(0);

      // E = fexp2(sacc) packed in-lane as GEMM2 B-operand; GEMM2 per ks
#pragma unroll
      for (int ks = 0; ks < 2; ++ks) {
        half8 ef[2];
#pragma unroll
        for (int nf = 0; nf < 2; ++nf)
#pragma unroll
          for (int e = 0; e < 8; ++e)
            ef[nf][e] = (_Float16)fexp2(sacc[2 * ks + (e >> 2)][nf][e & 3]);
        __builtin_amdgcn_s_setprio(1);
#pragma unroll
        for (int cf = 0; cf < 4; ++cf)
#pragma unroll
          for (int nf = 0; nf < 2; ++nf)
            oacc[j][cf][nf] = __builtin_amdgcn_mfma_f32_16x16x32_f16(
                wfr[cf][ks], ef[nf], oacc[j][cf][nf], 0, 0, 0);
        __builtin_amdgcn_s_setprio(0);
      }
    }
  }

  float* ob = out + b * CC * HWN;
#pragma unroll
  for (int j = 0; j < 2; ++j)
#pragma unroll
    for (int cf = 0; cf < 4; ++cf)
#pragma unroll
      for (int nf = 0; nf < 2; ++nf)
#pragma unroll
        for (int r = 0; r < 4; ++r) {
          int c = cf * 16 + lhi * 4 + r;
          int n = (nb0 + j) * 32 + nf * 16 + l15;
          ob[c * HWN + n] = oacc[j][cf][nf][r] * INV_SCALE;
        }
}

extern "C" void kernel_launch(void* const* d_in, const int* in_sizes, int n_in,
                              void* d_out, int out_size, void* d_ws, size_t ws_size,
                              hipStream_t stream) {
  const float* K = (const float*)d_in[0];
  const float* Q = (const float*)d_in[1];
  const float* V = (const float*)d_in[2];
  float* out = (float*)d_out;
  char* ws = (char*)d_ws;
  _Float16* kptF  = (_Float16*)(ws);                          // 294912 B
  float*    vp    = (float*)(ws + 294912);                    // 589824 B
  _Float16* wqF   = (_Float16*)(ws + 294912 + 589824);        // 294912 B
  float*    colsum = (float*)(ws + 294912 + 589824 + 294912); // 9216 B
  const size_t QF_OFF = 1204224;                              // 256B-aligned
  _Float16* qF = (_Float16*)(ws + QF_OFF);                    // 18.87 MB
  float* part  = out;                 // 5.31 MB scratch in dead d_out region
  float* part2 = out + 2097152;       // +8 MiB: 331 KB level-A partials

  pool_kernel<<<(2 * BB * CC * MP) / 256, 256, 0, stream>>>(K, V, kptF, vp);
  qprep_kernel<<<(BB * NBTOT * 4 * 64) / 256, 256, 0, stream>>>(Q, qF);
  colsum_qf2_kernel<<<(BB * NUNIT) / 4, 256, 0, stream>>>(qF, kptF, part);
  colsum_reduceA_kernel<<<dim3(NGRP, BB), 576, 0, stream>>>(part, part2);
  colsum_reduceB_kernel<<<(BB * MP) / 256, 256, 0, stream>>>(part2, colsum);
  wprep_kernel<<<(BB * CC * MP) / 256, 256, 0, stream>>>(vp, colsum, wqF);
  attn_v4_kernel<<<dim3(NBTOT / 8, BB), 256, 0, stream>>>(qF, kptF, wqF, out);
}

// Round 19
// 82.418 us; speedup vs baseline: 1.0280x; 1.0280x over previous
//
#include <hip/hip_runtime.h>
#include <stdint.h>

#define BB 4
#define CC 64
#define HH 192
#define WW 192
#define HWN (HH*WW)            // 36864
#define KH 4
#define KW 16
#define PW (WW/KW)             // 12
#define MP ((HH/KH)*(WW/KW))   // 576
#define MITER (MP/64)          // 9
#define NBTOT (HWN/32)         // 1152 32-row n-blocks per batch
#define NUNIT (HWN/64)         // 576 64-row units per batch (colsum)
#define NGRP 36                // reduce level-A groups (16 un each)
#define SCALE_W 65536.0f
#define INV_SCALE (1.0f/65536.0f)
#define LOG2E 1.44269504088896f

typedef _Float16 half8 __attribute__((ext_vector_type(8)));
typedef float floatx4 __attribute__((ext_vector_type(4)));

// async global->LDS, 16B per lane; LDS dest = uniform base + lane*16 (HW rule)
static __device__ __forceinline__ void gload16(const void* g, void* l) {
  __builtin_amdgcn_global_load_lds((const __attribute__((address_space(1))) void*)g,
                                   (__attribute__((address_space(3))) void*)l, 16, 0, 0);
}
#define WAITCNT_VM(N) asm volatile("s_waitcnt vmcnt(" #N ")" ::: "memory")

// fast 2^x: raw v_exp_f32 (libm exp2f costs ~15 VALU ops without fast-math)
static __device__ __forceinline__ float fexp2(float x) {
#if __has_builtin(__builtin_amdgcn_exp2f)
  return __builtin_amdgcn_exp2f(x);
#else
  return __expf(x * 0.6931471805599453f);
#endif
}

// Layouts (frag slot = chunk*512 + (lhi*16+l15)*8 + e, f16):
// kptF chunk=(mi*4+mf)*2+ks : Kp[b][m=mi*64+mf*16+l15][c=ks*32+lhi*8+e] * LOG2E
// qF   chunk=(b*NBTOT+nb)*4+ks*2+nf : Q[b][c=ks*32+lhi*8+e][n=nb*32+nf*16+l15]
// wqF  chunk=(mi*4+cf)*2+ks : W'[b][c=cf*16+l15][m=mi*64+ks*32+16*(e>>2)+lhi*4+(e&3)]
//   (sigma k-order: GEMM2's B-operand (E^T) is the IN-LANE repack of swapped-
//    GEMM1's accumulator -- slot e of window ks = exp2(sacc[2ks+(e>>2)][nf][e&3]))

// ------- fused prep: pool (K->kptF, V->vp) + qprep (Q->qF), one launch -----
__global__ __launch_bounds__(256) void prep_kernel(
    const float* __restrict__ Kin, const float* __restrict__ Vin,
    const float* __restrict__ Q,
    _Float16* __restrict__ kptF, float* __restrict__ vp,
    _Float16* __restrict__ qF) {
  const int POOL_BLOCKS = (2 * BB * CC * MP) / 256;  // 1152
  if (blockIdx.x < POOL_BLOCKS) {
    int t = blockIdx.x * 256 + threadIdx.x;
    const int total = BB * CC * MP;
    bool isV = t >= total;
    int idx = isV ? t - total : t;
    int m = idx % MP;
    int c = (idx / MP) % CC;
    int b = idx / (MP * CC);
    int mh = m / PW, mw = m % PW;
    const float* src = (isV ? Vin : Kin) + (((b * CC + c) * HH + mh * KH) * WW + mw * KW);
    float s = 0.f;
#pragma unroll
    for (int r = 0; r < KH; ++r) {
      const float4* row = (const float4*)(src + r * WW);
#pragma unroll
      for (int j = 0; j < KW / 4; ++j) {
        float4 v = row[j];
        s += v.x + v.y + v.z + v.w;
      }
    }
    s *= (1.0f / (KH * KW));
    if (isV) {
      vp[(b * CC + c) * MP + m] = s;
    } else {
      int mi = m >> 6, w = m & 63, mf = w >> 4, l15 = w & 15;
      int ks = c >> 5, lhi = (c >> 3) & 3, e = c & 7;
      int lane = lhi * 16 + l15;
      kptF[((((b * MITER + mi) * 4 + mf) * 2 + ks) * 64 + lane) * 8 + e] =
          (_Float16)(s * LOG2E);
    }
  } else {
    int t = (blockIdx.x - POOL_BLOCKS) * 256 + threadIdx.x;
    int chunk = t >> 6;
    int lane = t & 63;
    int nf = chunk & 1;
    int ks = (chunk >> 1) & 1;
    int idx = chunk >> 2;          // b*NBTOT + nb
    int nb = idx % NBTOT;
    int b = idx / NBTOT;
    int c0 = ks * 32 + (lane >> 4) * 8;
    int n = nb * 32 + nf * 16 + (lane & 15);
    const float* Qb = Q + (b * CC + c0) * HWN + n;
    half8 h;
#pragma unroll
    for (int e = 0; e < 8; ++e) h[e] = (_Float16)Qb[e * HWN];
    *(half8*)(qF + chunk * 512 + lane * 8) = h;
  }
}

// ---------------- pass A1: partial colsum (qF once per wave) ---------------
__global__ __launch_bounds__(256) void colsum_qf2_kernel(
    const _Float16* __restrict__ qF, const _Float16* __restrict__ kptF,
    float* __restrict__ part) {
  int tid = threadIdx.x;
  int lane = tid & 63;
  int l15 = lane & 15;
  int u = blockIdx.x * 4 + (tid >> 6);   // 0..BB*NUNIT-1
  int b = u / NUNIT;
  int un = u % NUNIT;

  const _Float16* qc = qF + (size_t)((b * NBTOT + un * 2) * 4) * 512 + lane * 8;
  half8 af[2][2][2];  // [nb][nf][ks]
#pragma unroll
  for (int nb = 0; nb < 2; ++nb)
#pragma unroll
    for (int ks = 0; ks < 2; ++ks)
#pragma unroll
      for (int nf = 0; nf < 2; ++nf)
        af[nb][nf][ks] = *(const half8*)(qc + (nb * 4 + ks * 2 + nf) * 512);

  const _Float16* kb = kptF + b * MITER * 8 * 512;
  floatx4 zero = {0.f, 0.f, 0.f, 0.f};
  float* pout = part + (size_t)(b * NUNIT + un) * MP;

#pragma unroll
  for (int mi = 0; mi < MITER; ++mi) {
    half8 bfr[4][2];
#pragma unroll
    for (int mf = 0; mf < 4; ++mf)
#pragma unroll
      for (int ks = 0; ks < 2; ++ks)
        bfr[mf][ks] = *(const half8*)(kb + ((mi * 4 + mf) * 2 + ks) * 512 + lane * 8);

    float s0 = 0.f, s1 = 0.f, s2 = 0.f, s3 = 0.f;
#pragma unroll
    for (int nb = 0; nb < 2; ++nb) {
      floatx4 sacc[2][4];
#pragma unroll
      for (int nf = 0; nf < 2; ++nf)
#pragma unroll
        for (int mf = 0; mf < 4; ++mf) sacc[nf][mf] = zero;
      __builtin_amdgcn_s_setprio(1);
#pragma unroll
      for (int ks = 0; ks < 2; ++ks)
#pragma unroll
        for (int nf = 0; nf < 2; ++nf)
#pragma unroll
          for (int mf = 0; mf < 4; ++mf)
            sacc[nf][mf] = __builtin_amdgcn_mfma_f32_16x16x32_f16(
                af[nb][nf][ks], bfr[mf][ks], sacc[nf][mf], 0, 0, 0);
      __builtin_amdgcn_s_setprio(0);
#pragma unroll
      for (int nf = 0; nf < 2; ++nf)
#pragma unroll
        for (int r = 0; r < 4; ++r) {
          s0 += fexp2(sacc[nf][0][r]);
          s1 += fexp2(sacc[nf][1][r]);
          s2 += fexp2(sacc[nf][2][r]);
          s3 += fexp2(sacc[nf][3][r]);
        }
    }
    s0 += __shfl_xor(s0, 16); s0 += __shfl_xor(s0, 32);
    s1 += __shfl_xor(s1, 16); s1 += __shfl_xor(s1, 32);
    s2 += __shfl_xor(s2, 16); s2 += __shfl_xor(s2, 32);
    s3 += __shfl_xor(s3, 16); s3 += __shfl_xor(s3, 32);
    if (lane < 16) {
      float* p = pout + mi * 64;
      p[0 * 16 + l15] = s0;   // m = mi*64 + mf*16 + l15
      p[1 * 16 + l15] = s1;
      p[2 * 16 + l15] = s2;
      p[3 * 16 + l15] = s3;
    }
  }
}

// ---------------- pass A2a: level-A reduce (144 blocks, 16 un each) --------
__global__ __launch_bounds__(576) void colsum_reduceA_kernel(
    const float* __restrict__ part, float* __restrict__ part2) {
  int m = threadIdx.x;           // 0..575
  int g = blockIdx.x;            // 0..35
  int b = blockIdx.y;
  const float* p = part + (size_t)(b * NUNIT + g * 16) * MP + m;
  float a0 = 0.f, a1 = 0.f, a2 = 0.f, a3 = 0.f;
#pragma unroll
  for (int j = 0; j < 16; j += 4) {
    a0 += p[(size_t)(j + 0) * MP];
    a1 += p[(size_t)(j + 1) * MP];
    a2 += p[(size_t)(j + 2) * MP];
    a3 += p[(size_t)(j + 3) * MP];
  }
  part2[(size_t)(b * NGRP + g) * MP + m] = (a0 + a1) + (a2 + a3);
}

// ---------------- pass A2b: level-B reduce (36 summands) -------------------
__global__ __launch_bounds__(256) void colsum_reduceB_kernel(
    const float* __restrict__ part2, float* __restrict__ colsum) {
  int t = blockIdx.x * 256 + threadIdx.x;  // 0..2303
  int m = t % MP;
  int b = t / MP;
  const float* p = part2 + (size_t)b * NGRP * MP + m;
  float a0 = 0.f, a1 = 0.f, a2 = 0.f, a3 = 0.f;
#pragma unroll
  for (int g = 0; g < NGRP; g += 4) {
    a0 += p[(size_t)(g + 0) * MP];
    a1 += p[(size_t)(g + 1) * MP];
    a2 += p[(size_t)(g + 2) * MP];
    a3 += p[(size_t)(g + 3) * MP];
  }
  colsum[t] = (a0 + a1) + (a2 + a3);
}

// ---------------- W' = Vp/colsum * 2^16 (f16, sigma-permuted k-order) ------
__global__ __launch_bounds__(256) void wprep_kernel(
    const float* __restrict__ vp, const float* __restrict__ colsum,
    _Float16* __restrict__ wqF) {
  int t = blockIdx.x * 256 + threadIdx.x;
  int m = t % MP;
  int c = (t / MP) % CC;
  int b = t / (CC * MP);
  float w = vp[t] / colsum[b * MP + m] * SCALE_W;
  int cf = c >> 4, l15 = c & 15;
  int mi = m >> 6, wl = m & 63;
  int ks = wl >> 5, v = wl & 31;
  int lhi = (v & 15) >> 2;
  int e = (v >> 4) * 4 + (v & 3);
  int lane = lhi * 16 + l15;
  wqF[((((b * MITER + mi) * 4 + cf) * 2 + ks) * 64 + lane) * 8 + e] = (_Float16)w;
}

// ---------------- pass B: attn v5 — counted vmcnt, 3-slot ring -------------
// v4 body (2 j-chains, E-eliminated) + T3/T4: stage tile mi+2 each body,
// vmcnt(4) at body top (tile mi+1's loads stay in flight ACROSS the barrier),
// vmcnt(0) only at the last body. Slot reuse safe: a wave at barrier(mi) has
// consumed its body-(mi-1) ds_reads via MFMA, so slot (mi+2)%3==(mi-1)%3 is
// free for restage after the barrier.
__global__ __launch_bounds__(256) void attn_v5_kernel(
    const _Float16* __restrict__ qF, const _Float16* __restrict__ kptF,
    const _Float16* __restrict__ wqF, float* __restrict__ out) {
  __shared__ char stg[3 * 16384];  // 48KB
  int b = blockIdx.y;
  int tid = threadIdx.x;
  int wv = tid >> 6;
  int lane = tid & 63;
  int l15 = lane & 15, lhi = lane >> 4;

  const _Float16* kb = kptF + b * MITER * 8 * 512;
  const _Float16* wb = wqF + b * MITER * 8 * 512;

#define STAGE_V5(tt, ss)                                                       \
  {                                                                            \
    int q0_ = wv * 4;                                                          \
    _Pragma("unroll") for (int j_ = 0; j_ < 4; ++j_) {                         \
      int q_ = q0_ + j_;                                                       \
      const _Float16* sp_ = (q_ < 8 ? kb + (tt) * 4096 + q_ * 512              \
                                    : wb + (tt) * 4096 + (q_ - 8) * 512) +     \
                            lane * 8;                                          \
      gload16(sp_, stg + (ss) * 16384 + q_ * 1024);                            \
    }                                                                          \
  }

  // prologue: afrag loads + stage tiles 0,1 (12 vmem ops outstanding)
  int nb0 = blockIdx.x * 8 + wv * 2;   // wave owns n-blocks nb0, nb0+1
  const _Float16* qc = qF + (size_t)((b * NBTOT + nb0) * 4) * 512 + lane * 8;
  half8 afrag[2][2][2];  // [j][nf][ks]
#pragma unroll
  for (int j = 0; j < 2; ++j)
#pragma unroll
    for (int ks = 0; ks < 2; ++ks)
#pragma unroll
      for (int nf = 0; nf < 2; ++nf)
        afrag[j][nf][ks] = *(const half8*)(qc + (j * 4 + ks * 2 + nf) * 512);
  STAGE_V5(0, 0);
  STAGE_V5(1, 1);

  floatx4 zero = {0.f, 0.f, 0.f, 0.f};
  floatx4 oacc[2][4][2];  // [j][cf][nf]
#pragma unroll
  for (int j = 0; j < 2; ++j)
#pragma unroll
    for (int cf = 0; cf < 4; ++cf)
#pragma unroll
      for (int nf = 0; nf < 2; ++nf) oacc[j][cf][nf] = zero;

#pragma unroll
  for (int mi = 0; mi < MITER; ++mi) {
    const int sc = mi % 3;
    // counted drain: tile mi landed; tile mi+1's 4 loads may stay in flight
    if (mi < MITER - 1) { WAITCNT_VM(4); } else { WAITCNT_VM(0); }
    __builtin_amdgcn_sched_barrier(0);
    __builtin_amdgcn_s_barrier();
    if (mi + 2 < MITER) STAGE_V5(mi + 2, (mi + 2) % 3);

    half8 bfr[4][2];  // kpt A-operand: rows m
#pragma unroll
    for (int mf = 0; mf < 4; ++mf)
#pragma unroll
      for (int ks = 0; ks < 2; ++ks)
        bfr[mf][ks] = *(const half8*)(stg + sc * 16384 + (mf * 2 + ks) * 1024 + lane * 16);
    half8 wfr[4][2];  // W' A-operand (sigma k-order)
#pragma unroll
    for (int cf = 0; cf < 4; ++cf)
#pragma unroll
      for (int ks = 0; ks < 2; ++ks)
        wfr[cf][ks] = *(const half8*)(stg + sc * 16384 + 8192 + (cf * 2 + ks) * 1024 + lane * 16);

#pragma unroll
    for (int j = 0; j < 2; ++j) {
      // GEMM1 (swapped): sacc[mf][nf] = S^T tile for n-block nb0+j
      floatx4 sacc[4][2];
#pragma unroll
      for (int mf = 0; mf < 4; ++mf)
#pragma unroll
        for (int nf = 0; nf < 2; ++nf) sacc[mf][nf] = zero;
      __builtin_amdgcn_s_setprio(1);
#pragma unroll
      for (int ks = 0; ks < 2; ++ks)
#pragma unroll
        for (int mf = 0; mf < 4; ++mf)
#pragma unroll
          for (int nf = 0; nf < 2; ++nf)
            sacc[mf][nf] = __builtin_amdgcn_mfma_f32_16x16x32_f16(
                bfr[mf][ks], afrag[j][nf][ks], sacc[mf][nf], 0, 0, 0);
      __builtin_amdgcn_s_setprio(0);

      // E = fexp2(sacc) packed in-lane as GEMM2 B-operand; GEMM2 per ks
#pragma unroll
      for (int ks = 0; ks < 2; ++ks) {
        half8 ef[2];
#pragma unroll
        for (int nf = 0; nf < 2; ++nf)
#pragma unroll
          for (int e = 0; e < 8; ++e)
            ef[nf][e] = (_Float16)fexp2(sacc[2 * ks + (e >> 2)][nf][e & 3]);
        __builtin_amdgcn_s_setprio(1);
#pragma unroll
        for (int cf = 0; cf < 4; ++cf)
#pragma unroll
          for (int nf = 0; nf < 2; ++nf)
            oacc[j][cf][nf] = __builtin_amdgcn_mfma_f32_16x16x32_f16(
                wfr[cf][ks], ef[nf], oacc[j][cf][nf], 0, 0, 0);
        __builtin_amdgcn_s_setprio(0);
      }
    }
  }

  float* ob = out + b * CC * HWN;
#pragma unroll
  for (int j = 0; j < 2; ++j)
#pragma unroll
    for (int cf = 0; cf < 4; ++cf)
#pragma unroll
      for (int nf = 0; nf < 2; ++nf)
#pragma unroll
        for (int r = 0; r < 4; ++r) {
          int c = cf * 16 + lhi * 4 + r;
          int n = (nb0 + j) * 32 + nf * 16 + l15;
          ob[c * HWN + n] = oacc[j][cf][nf][r] * INV_SCALE;
        }
}

extern "C" void kernel_launch(void* const* d_in, const int* in_sizes, int n_in,
                              void* d_out, int out_size, void* d_ws, size_t ws_size,
                              hipStream_t stream) {
  const float* K = (const float*)d_in[0];
  const float* Q = (const float*)d_in[1];
  const float* V = (const float*)d_in[2];
  float* out = (float*)d_out;
  char* ws = (char*)d_ws;
  _Float16* kptF  = (_Float16*)(ws);                          // 294912 B
  float*    vp    = (float*)(ws + 294912);                    // 589824 B
  _Float16* wqF   = (_Float16*)(ws + 294912 + 589824);        // 294912 B
  float*    colsum = (float*)(ws + 294912 + 589824 + 294912); // 9216 B
  const size_t QF_OFF = 1204224;                              // 256B-aligned
  _Float16* qF = (_Float16*)(ws + QF_OFF);                    // 18.87 MB
  float* part  = out;                 // 5.31 MB scratch in dead d_out region
  float* part2 = out + 2097152;       // +8 MiB: 331 KB level-A partials

  const int POOL_BLOCKS = (2 * BB * CC * MP) / 256;           // 1152
  const int QPREP_BLOCKS = (BB * NBTOT * 4 * 64) / 256;       // 1152
  prep_kernel<<<POOL_BLOCKS + QPREP_BLOCKS, 256, 0, stream>>>(K, V, Q, kptF, vp, qF);
  colsum_qf2_kernel<<<(BB * NUNIT) / 4, 256, 0, stream>>>(qF, kptF, part);
  colsum_reduceA_kernel<<<dim3(NGRP, BB), 576, 0, stream>>>(part, part2);
  colsum_reduceB_kernel<<<(BB * MP) / 256, 256, 0, stream>>>(part2, colsum);
  wprep_kernel<<<(BB * CC * MP) / 256, 256, 0, stream>>>(vp, colsum, wqF);
  attn_v5_kernel<<<dim3(NBTOT / 8, BB), 256, 0, stream>>>(qF, kptF, wqF, out);
}